// Round 9
// baseline (308.260 us; speedup 1.0000x reference)
//
#include <hip/hip_runtime.h>
#include <cstdint>

typedef __attribute__((ext_vector_type(8))) _Float16 half8;
typedef __attribute__((ext_vector_type(4))) _Float16 half4;
typedef __attribute__((ext_vector_type(4))) float f32x4;

// ---------------- weight prep: fp32 W -> permuted-K fp16 hi/lo A-fragments ----------------
// k-slot (g,e) of k-step kp holds feature f = (2kp + (e>>2))*16 + 4g + (e&3).
// Layout: wf[(Lid*2+kp)*2 + plane][lane][mt][e]  (2048 halves per plane-frag)
__global__ void prep_weights(const float* __restrict__ cWh, const float* __restrict__ cWo,
                             const float* __restrict__ sWh, const float* __restrict__ sWo,
                             _Float16* __restrict__ wf) {
    int t = blockIdx.x * 256 + threadIdx.x;  // 0..32767
    int e    = t & 7;
    int mt   = (t >> 3) & 3;
    int lane = (t >> 5) & 63;
    int kp   = (t >> 11) & 1;
    int L    = (t >> 12) & 7;
    const float* src = (L < 3)  ? cWh + L * 4096
                     : (L == 3) ? cWo
                     : (L < 7)  ? sWh + (L - 4) * 4096
                     :            sWo;
    int m = mt * 16 + (lane & 15);
    int k = (2 * kp + (e >> 2)) * 16 + 4 * (lane >> 4) + (e & 3);
    float w = src[m * 64 + k];
    _Float16 hi = (_Float16)w;            // RTNE hardware cvt
    _Float16 lo = (_Float16)(w - (float)hi);
    int off = lane * 32 + mt * 8 + e;
    int fi = (L * 2 + kp) * 2;
    wf[fi * 2048 + off]       = hi;
    wf[(fi + 1) * 2048 + off] = lo;
}

// build one fp16 B-fragment from two f32x4 acc tiles (k-tiles 2kp, 2kp+1), with optional relu
template<bool RELU>
__device__ __forceinline__ half8 cvt_frag(f32x4 a, f32x4 b) {
    half8 r;
#pragma unroll
    for (int i = 0; i < 4; ++i) {
        float va = RELU ? fmaxf(a[i], 0.f) : a[i];
        float vb = RELU ? fmaxf(b[i], 0.f) : b[i];
        r[i]     = (_Float16)va;
        r[i + 4] = (_Float16)vb;
    }
    return r;
}

// ---------------- one MLP layer (32 samples/wave): 2-term weights x 1-term activations ----------------
__device__ __forceinline__ void run_layer(const _Float16* __restrict__ wf, int Lid,
                                          const float* __restrict__ bias, int lane, int g4,
                                          const half8 B[2][2], f32x4 acc[4][2]) {
#pragma unroll
    for (int mt = 0; mt < 4; ++mt) {
        f32x4 bb = *(const f32x4*)(bias + mt * 16 + g4);
#pragma unroll
        for (int nt = 0; nt < 2; ++nt) acc[mt][nt] = bb;
    }
#pragma unroll
    for (int kp = 0; kp < 2; ++kp) {
        half8 Ah[4], Al[4];
        const _Float16* p = wf + (Lid * 2 + kp) * 4096 + lane * 32;
#pragma unroll
        for (int mt = 0; mt < 4; ++mt) {
            Ah[mt] = *(const half8*)(p + mt * 8);
            Al[mt] = *(const half8*)(p + 2048 + mt * 8);
        }
#pragma unroll
        for (int nt = 0; nt < 2; ++nt)
#pragma unroll
            for (int mt = 0; mt < 4; ++mt) {
                acc[mt][nt] = __builtin_amdgcn_mfma_f32_16x16x32_f16(Ah[mt], B[kp][nt], acc[mt][nt], 0, 0, 0);
                acc[mt][nt] = __builtin_amdgcn_mfma_f32_16x16x32_f16(Al[mt], B[kp][nt], acc[mt][nt], 0, 0, 0);
            }
    }
}

__device__ __forceinline__ void acc_to_B_relu(const f32x4 acc[4][2], half8 B[2][2]) {
#pragma unroll
    for (int kp = 0; kp < 2; ++kp)
#pragma unroll
        for (int nt = 0; nt < 2; ++nt)
            B[kp][nt] = cvt_frag<true>(acc[2 * kp][nt], acc[2 * kp + 1][nt]);
}

// build B0 (x_masked) fragments straight from global; optionally write passthrough
template<bool WRITE_Y>
__device__ __forceinline__ void load_B0(const float* __restrict__ xr, float* __restrict__ yr,
                                        half8 B[2][2]) {
#pragma unroll
    for (int nt = 0; nt < 2; ++nt) {
        f32x4 v0 = *(const f32x4*)(xr + nt * 2048);
        f32x4 v1 = *(const f32x4*)(xr + nt * 2048 + 16);
        f32x4 v2 = *(const f32x4*)(xr + nt * 2048 + 32);
        f32x4 v3 = *(const f32x4*)(xr + nt * 2048 + 48);
        if (WRITE_Y) {
            __builtin_nontemporal_store(v0, (f32x4*)(yr + nt * 2048));
            __builtin_nontemporal_store(v1, (f32x4*)(yr + nt * 2048 + 16));
            __builtin_nontemporal_store(v2, (f32x4*)(yr + nt * 2048 + 32));
            __builtin_nontemporal_store(v3, (f32x4*)(yr + nt * 2048 + 48));
        }
        B[0][nt] = cvt_frag<false>(v0, v1);
        B[1][nt] = cvt_frag<false>(v2, v3);
    }
}

// ---------------- main kernel: 1 wave = 32 rows, 1-wave blocks, 4 waves/SIMD, no LDS ----------------
__global__ __launch_bounds__(64, 4)
void coupling_main(const float* __restrict__ x,
                   const float* __restrict__ cbh, const float* __restrict__ cbo,
                   const float* __restrict__ sbh, const float* __restrict__ sbo,
                   const _Float16* __restrict__ wf,
                   float* __restrict__ y, float* __restrict__ logdet) {
    const int lane = threadIdx.x;
    const int c = lane & 15;
    const int g4 = (lane >> 4) * 4;
    const long row0 = (long)blockIdx.x * 32;
    const float* xr = x + (row0 + c) * 128 + g4;
    float* yr = y + (row0 + c) * 128 + g4;

    f32x4 acc[4][2];
    half8 B[2][2];

    // prologue: read x_masked, passthrough to y[:, :64], build B0 (not parked)
    load_B0<true>(xr, yr, B);

    // cond MLP (ids 0..3) -> shift (parked as fp16, 16 regs)
    run_layer(wf, 0, cbh,       lane, g4, B, acc);
    acc_to_B_relu(acc, B);
    run_layer(wf, 1, cbh + 64,  lane, g4, B, acc);
    acc_to_B_relu(acc, B);
    run_layer(wf, 2, cbh + 128, lane, g4, B, acc);
    acc_to_B_relu(acc, B);
    run_layer(wf, 3, cbo,       lane, g4, B, acc);
    half4 shp[4][2];
#pragma unroll
    for (int mt = 0; mt < 4; ++mt)
#pragma unroll
        for (int nt = 0; nt < 2; ++nt) {
            half4 s;
#pragma unroll
            for (int i = 0; i < 4; ++i) s[i] = (_Float16)acc[mt][nt][i];
            shp[mt][nt] = s;
        }

    // rebuild B0 from cache (x row is L3-hot; passthrough was NT so L3 not polluted)
    load_B0<false>(xr, yr, B);

    // scale MLP (ids 4..7) -> log_scale in acc
    run_layer(wf, 4, sbh,       lane, g4, B, acc);
    acc_to_B_relu(acc, B);
    run_layer(wf, 5, sbh + 64,  lane, g4, B, acc);
    acc_to_B_relu(acc, B);
    run_layer(wf, 6, sbh + 128, lane, g4, B, acc);
    acc_to_B_relu(acc, B);
    run_layer(wf, 7, sbo,       lane, g4, B, acc);

    // epilogue: y[:,64:] = x_t * exp(clip(ls,-5,3)) + shift ; logdet = sum(ls unclipped)
    float pld0 = 0.f, pld1 = 0.f;
#pragma unroll
    for (int nt = 0; nt < 2; ++nt) {
        float psum = 0.f;
#pragma unroll
        for (int mt = 0; mt < 4; ++mt) {
            f32x4 ls = acc[mt][nt];
            psum += ls[0] + ls[1] + ls[2] + ls[3];
            f32x4 xt = *(const f32x4*)(xr + nt * 2048 + 64 + mt * 16);
            half4 sp = shp[mt][nt];
            f32x4 o;
#pragma unroll
            for (int i = 0; i < 4; ++i) {
                float cl = fminf(fmaxf(ls[i], -5.f), 3.f);
                o[i] = xt[i] * __expf(cl) + (float)sp[i];
            }
            __builtin_nontemporal_store(o, (f32x4*)(yr + nt * 2048 + 64 + mt * 16));
        }
        if (nt == 0) pld0 = psum; else pld1 = psum;
    }
#pragma unroll
    for (int nt = 0; nt < 2; ++nt) {
        float v = (nt == 0) ? pld0 : pld1;
        v += __shfl_xor(v, 16);
        v += __shfl_xor(v, 32);
        if ((lane >> 4) == 0) logdet[row0 + nt * 16 + c] = v;
    }
}

extern "C" void kernel_launch(void* const* d_in, const int* in_sizes, int n_in,
                              void* d_out, int out_size, void* d_ws, size_t ws_size,
                              hipStream_t stream) {
    const float* x   = (const float*)d_in[0];
    const float* cWh = (const float*)d_in[1];
    const float* cbh = (const float*)d_in[2];
    const float* cWo = (const float*)d_in[3];
    const float* cbo = (const float*)d_in[4];
    const float* sWh = (const float*)d_in[5];
    const float* sbh = (const float*)d_in[6];
    const float* sWo = (const float*)d_in[7];
    const float* sbo = (const float*)d_in[8];

    const int B = in_sizes[0] / 128;  // 524288

    _Float16* wf = (_Float16*)d_ws;  // 8 layers * 2 kp * 2 planes * 2048 halves = 128 KB

    prep_weights<<<128, 256, 0, stream>>>(cWh, cWo, sWh, sWo, wf);

    float* y = (float*)d_out;
    float* logdet = y + (size_t)B * 128;
    coupling_main<<<B / 32, 64, 0, stream>>>(x, cbh, cbo, sbh, sbo, wf, y, logdet);
}

// Round 10
// 177.247 us; speedup vs baseline: 1.7392x; 1.7392x over previous
//
#include <hip/hip_runtime.h>
#include <cstdint>

typedef __attribute__((ext_vector_type(8))) _Float16 half8;
typedef __attribute__((ext_vector_type(4))) _Float16 half4;
typedef __attribute__((ext_vector_type(4))) float f32x4;
typedef __attribute__((ext_vector_type(4))) unsigned int u32x4;

// ---------------- prep: build the exact 130 KB LDS image in d_ws ----------------
// bytes [0,131072): 32 fragment planes fi = (L*2+kp)*2 + plane(hi=0,lo=1);
//                   plane layout [mt(4)][lane(64)] x 16B chunks (8 halves, e=0..7)
//                   chunk value: W[mt*16+(lane&15)][ (2kp+(e>>2))*16 + 4*(lane>>4) + (e&3) ]
// bytes [131072,133120): biases f32 [L(8)][feat(64)]
__global__ void prep_weights(const float* __restrict__ cWh, const float* __restrict__ cWo,
                             const float* __restrict__ sWh, const float* __restrict__ sWo,
                             const float* __restrict__ cbh, const float* __restrict__ cbo,
                             const float* __restrict__ sbh, const float* __restrict__ sbo,
                             char* __restrict__ img) {
    int t = blockIdx.x * 256 + threadIdx.x;  // 0..33279
    if (t < 32768) {
        int e = t & 7, mt = (t >> 3) & 3, lane = (t >> 5) & 63, kp = (t >> 11) & 1, L = (t >> 12) & 7;
        const float* src = (L < 3)  ? cWh + L * 4096
                         : (L == 3) ? cWo
                         : (L < 7)  ? sWh + (L - 4) * 4096
                         :            sWo;
        int m = mt * 16 + (lane & 15);
        int k = (2 * kp + (e >> 2)) * 16 + 4 * (lane >> 4) + (e & 3);
        float w = src[m * 64 + k];
        _Float16 hi = (_Float16)w;                 // RTNE hardware cvt
        _Float16 lo = (_Float16)(w - (float)hi);
        _Float16* wf = (_Float16*)img;
        int fi = (L * 2 + kp) * 2;
        wf[((fi * 4 + mt) * 64 + lane) * 8 + e]       = hi;
        wf[(((fi + 1) * 4 + mt) * 64 + lane) * 8 + e] = lo;
    } else if (t < 33280) {
        int b = t - 32768;  // L*64 + feat
        int L = b >> 6, f = b & 63;
        const float* src = (L < 3)  ? cbh + L * 64
                         : (L == 3) ? cbo
                         : (L < 7)  ? sbh + (L - 4) * 64
                         :            sbo;
        ((float*)(img + 131072))[b] = src[f];
    }
}

// build one fp16 B-fragment from two f32x4 acc tiles (k-tiles 2kp, 2kp+1), optional relu
template<bool RELU>
__device__ __forceinline__ half8 cvt_frag(f32x4 a, f32x4 b) {
    half8 r;
#pragma unroll
    for (int i = 0; i < 4; ++i) {
        float va = RELU ? fmaxf(a[i], 0.f) : a[i];
        float vb = RELU ? fmaxf(b[i], 0.f) : b[i];
        r[i]     = (_Float16)va;
        r[i + 4] = (_Float16)vb;
    }
    return r;
}

// ---------------- one MLP layer (64 samples/wave): weights+bias from LDS only ----------------
__device__ __forceinline__ void run_layer(const _Float16* __restrict__ lwf,
                                          const float* __restrict__ lb, int Lid,
                                          int lane, int g4,
                                          const half8 B[2][4], f32x4 acc[4][4]) {
#pragma unroll
    for (int mt = 0; mt < 4; ++mt) {
        f32x4 bb = *(const f32x4*)(lb + Lid * 64 + mt * 16 + g4);
#pragma unroll
        for (int nt = 0; nt < 4; ++nt) acc[mt][nt] = bb;
    }
#pragma unroll
    for (int kp = 0; kp < 2; ++kp) {
        const int fi = (Lid * 2 + kp) * 2;
        half8 Ah[4], Al[4];
#pragma unroll
        for (int mt = 0; mt < 4; ++mt) {
            Ah[mt] = *(const half8*)(lwf + ((fi * 4 + mt) * 64 + lane) * 8);
            Al[mt] = *(const half8*)(lwf + (((fi + 1) * 4 + mt) * 64 + lane) * 8);
        }
#pragma unroll
        for (int nt = 0; nt < 4; ++nt)
#pragma unroll
            for (int mt = 0; mt < 4; ++mt) {
                acc[mt][nt] = __builtin_amdgcn_mfma_f32_16x16x32_f16(Ah[mt], B[kp][nt], acc[mt][nt], 0, 0, 0);
                acc[mt][nt] = __builtin_amdgcn_mfma_f32_16x16x32_f16(Al[mt], B[kp][nt], acc[mt][nt], 0, 0, 0);
            }
    }
}

__device__ __forceinline__ void acc_to_B_relu(const f32x4 acc[4][4], half8 B[2][4]) {
#pragma unroll
    for (int kp = 0; kp < 2; ++kp)
#pragma unroll
        for (int nt = 0; nt < 4; ++nt)
            B[kp][nt] = cvt_frag<true>(acc[2 * kp][nt], acc[2 * kp + 1][nt]);
}

// ---------------- main: 8 waves/block, 64 rows/wave; weights in LDS; one barrier ----------------
__global__ __launch_bounds__(512)
void coupling_main(const float* __restrict__ x, const char* __restrict__ img,
                   float* __restrict__ y, float* __restrict__ logdet) {
    extern __shared__ char smem[];
    {   // cooperative copy of the 133120-byte weight+bias image (8320 uint4)
        const u32x4* s = (const u32x4*)img;
        u32x4* d = (u32x4*)smem;
        for (int i = threadIdx.x; i < 8320; i += 512) d[i] = s[i];
    }
    __syncthreads();
    const _Float16* lwf = (const _Float16*)smem;
    const float* lb = (const float*)(smem + 131072);

    const int lane = threadIdx.x & 63;
    const int wid = threadIdx.x >> 6;
    const int c = lane & 15;
    const int g4 = (lane >> 4) * 4;
    const long row0 = (long)blockIdx.x * 512 + wid * 64;
    const float* xr = x + (row0 + c) * 128 + g4;
    float* yr = y + (row0 + c) * 128 + g4;

    // prologue: read x_masked once, passthrough to y[:, :64], build B0 frags (parked, 32 regs)
    half8 B0[2][4];
#pragma unroll
    for (int nt = 0; nt < 4; ++nt) {
        f32x4 v0 = *(const f32x4*)(xr + nt * 2048);
        f32x4 v1 = *(const f32x4*)(xr + nt * 2048 + 16);
        f32x4 v2 = *(const f32x4*)(xr + nt * 2048 + 32);
        f32x4 v3 = *(const f32x4*)(xr + nt * 2048 + 48);
        __builtin_nontemporal_store(v0, (f32x4*)(yr + nt * 2048));
        __builtin_nontemporal_store(v1, (f32x4*)(yr + nt * 2048 + 16));
        __builtin_nontemporal_store(v2, (f32x4*)(yr + nt * 2048 + 32));
        __builtin_nontemporal_store(v3, (f32x4*)(yr + nt * 2048 + 48));
        B0[0][nt] = cvt_frag<false>(v0, v1);
        B0[1][nt] = cvt_frag<false>(v2, v3);
    }

    f32x4 acc[4][4];
    half8 B[2][4];

    // cond MLP (ids 0..3) -> shift (parked as fp16, 32 regs)
    run_layer(lwf, lb, 0, lane, g4, B0, acc);
    acc_to_B_relu(acc, B);
    run_layer(lwf, lb, 1, lane, g4, B, acc);
    acc_to_B_relu(acc, B);
    run_layer(lwf, lb, 2, lane, g4, B, acc);
    acc_to_B_relu(acc, B);
    run_layer(lwf, lb, 3, lane, g4, B, acc);
    half4 shp[4][4];
#pragma unroll
    for (int mt = 0; mt < 4; ++mt)
#pragma unroll
        for (int nt = 0; nt < 4; ++nt) {
            half4 s;
#pragma unroll
            for (int i = 0; i < 4; ++i) s[i] = (_Float16)acc[mt][nt][i];
            shp[mt][nt] = s;
        }

    // scale MLP (ids 4..7) -> log_scale in acc
    run_layer(lwf, lb, 4, lane, g4, B0, acc);
    acc_to_B_relu(acc, B);
    run_layer(lwf, lb, 5, lane, g4, B, acc);
    acc_to_B_relu(acc, B);
    run_layer(lwf, lb, 6, lane, g4, B, acc);
    acc_to_B_relu(acc, B);
    run_layer(lwf, lb, 7, lane, g4, B, acc);

    // epilogue: y[:,64:] = x_t * exp(clip(ls,-5,3)) + shift ; logdet = sum(ls unclipped)
    float pld0 = 0.f, pld1 = 0.f, pld2 = 0.f, pld3 = 0.f;
#pragma unroll
    for (int nt = 0; nt < 4; ++nt) {
        float psum = 0.f;
#pragma unroll
        for (int mt = 0; mt < 4; ++mt) {
            f32x4 ls = acc[mt][nt];
            psum += ls[0] + ls[1] + ls[2] + ls[3];
            f32x4 xt = *(const f32x4*)(xr + nt * 2048 + 64 + mt * 16);
            half4 sp = shp[mt][nt];
            f32x4 o;
#pragma unroll
            for (int i = 0; i < 4; ++i) {
                float cl = fminf(fmaxf(ls[i], -5.f), 3.f);
                o[i] = xt[i] * __expf(cl) + (float)sp[i];
            }
            __builtin_nontemporal_store(o, (f32x4*)(yr + nt * 2048 + 64 + mt * 16));
        }
        if (nt == 0) pld0 = psum; else if (nt == 1) pld1 = psum;
        else if (nt == 2) pld2 = psum; else pld3 = psum;
    }
#pragma unroll
    for (int nt = 0; nt < 4; ++nt) {
        float v = (nt == 0) ? pld0 : (nt == 1) ? pld1 : (nt == 2) ? pld2 : pld3;
        v += __shfl_xor(v, 16);
        v += __shfl_xor(v, 32);
        if ((lane >> 4) == 0) logdet[row0 + nt * 16 + c] = v;
    }
}

extern "C" void kernel_launch(void* const* d_in, const int* in_sizes, int n_in,
                              void* d_out, int out_size, void* d_ws, size_t ws_size,
                              hipStream_t stream) {
    const float* x   = (const float*)d_in[0];
    const float* cWh = (const float*)d_in[1];
    const float* cbh = (const float*)d_in[2];
    const float* cWo = (const float*)d_in[3];
    const float* cbo = (const float*)d_in[4];
    const float* sWh = (const float*)d_in[5];
    const float* sbh = (const float*)d_in[6];
    const float* sWo = (const float*)d_in[7];
    const float* sbo = (const float*)d_in[8];

    const int B = in_sizes[0] / 128;  // 524288
    const int LDS_BYTES = 133120;

    char* img = (char*)d_ws;  // 130 KB weight+bias image

    prep_weights<<<130, 256, 0, stream>>>(cWh, cWo, sWh, sWo, cbh, cbo, sbh, sbo, img);

    // opt-in to >64KB dynamic LDS (no-op/ignored if not required on ROCm)
    (void)hipFuncSetAttribute((const void*)coupling_main,
                              hipFuncAttributeMaxDynamicSharedMemorySize, LDS_BYTES);

    float* y = (float*)d_out;
    float* logdet = y + (size_t)B * 128;
    coupling_main<<<B / 512, 512, LDS_BYTES, stream>>>(x, img, y, logdet);
}